// Round 1
// baseline (463.334 us; speedup 1.0000x reference)
//
#include <hip/hip_runtime.h>

// EuclideanCodebook: argmin_k || x_n - emb_k ||^2, quantized = emb[code]
// x: [N=32768, D=256] f32, embedding_sum: [K=2048, D=256] f32, usage: [K] f32
// d_out: quantized [N*D] f32 followed by codes [N] (written as float)

#define EPSV 1e-5f
#define D 256
#define BN 64
#define BK 128
#define DC 64
#define TM 8
#define TK 4

// ---------------- prep: emb = sum / max(usage,eps); emb_t; ||e||^2 ----------
__global__ void prep_emb(const float* __restrict__ esum,
                         const float* __restrict__ usage,
                         float* __restrict__ emb,      // [K][D]
                         float* __restrict__ emb_t,    // [D][K]
                         float* __restrict__ enorm2,   // [K]
                         int K) {
    const int k = blockIdx.x;
    const int d = threadIdx.x;            // 256 threads == D
    const float u = fmaxf(usage[k], EPSV);
    const float e = esum[k * D + d] / u;
    emb[k * D + d] = e;
    emb_t[(size_t)d * K + k] = e;

    float s = e * e;
    #pragma unroll
    for (int off = 32; off > 0; off >>= 1) s += __shfl_down(s, off, 64);
    __shared__ float ws[4];
    if ((threadIdx.x & 63) == 0) ws[threadIdx.x >> 6] = s;
    __syncthreads();
    if (threadIdx.x == 0) enorm2[k] = ws[0] + ws[1] + ws[2] + ws[3];
}

// ---------------- main: tiled fp32 distance + running argmin ----------------
__global__ __launch_bounds__(256) void vq_argmin(
        const float* __restrict__ x,        // [N][D]
        const float* __restrict__ emb_t,    // [D][K]
        const float* __restrict__ enorm2,   // [K]
        float* __restrict__ codes_f,        // [N] float codes (d_out tail)
        int* __restrict__ codes_i,          // [N] int codes (ws, for gather)
        int K) {
    __shared__ float xs[BN * DC];           // 16 KB
    __shared__ float es[DC * BK];           // 32 KB, d-major: es[d][k]

    const int tid = threadIdx.x;
    const int tx  = tid & 31;               // cluster group: 32 x TK = BK
    const int ty  = tid >> 5;               // row group: 8 x TM = BN
    const int n0  = blockIdx.x * BN;

    float bestd[TM];
    int   bestk[TM];
    #pragma unroll
    for (int i = 0; i < TM; ++i) { bestd[i] = 3.0e38f; bestk[i] = 0; }

    const int NKT = K / BK;                 // 16
    for (int kt = 0; kt < NKT; ++kt) {
        const int k0 = kt * BK;
        float acc[TM][TK];
        #pragma unroll
        for (int i = 0; i < TM; ++i)
            #pragma unroll
            for (int j = 0; j < TK; ++j) acc[i][j] = 0.0f;

        for (int dc = 0; dc < D / DC; ++dc) {
            const int d0 = dc * DC;
            __syncthreads();
            // stage x tile: BN x DC = 1024 float4, 4 per thread
            #pragma unroll
            for (int it = 0; it < 4; ++it) {
                const int q = it * 256 + tid;
                const int r = q >> 4, c = q & 15;         // 16 float4 per row
                *(float4*)&xs[r * DC + c * 4] =
                    *(const float4*)&x[(size_t)(n0 + r) * D + d0 + c * 4];
            }
            // stage emb_t tile: DC x BK = 2048 float4, 8 per thread
            #pragma unroll
            for (int it = 0; it < 8; ++it) {
                const int q = it * 256 + tid;
                const int dd = q >> 5, c = q & 31;        // 32 float4 per row
                *(float4*)&es[dd * BK + c * 4] =
                    *(const float4*)&emb_t[(size_t)(d0 + dd) * K + k0 + c * 4];
            }
            __syncthreads();

            #pragma unroll
            for (int step = 0; step < DC / 4; ++step) {
                // 4 cluster-values (this thread's TK=4 clusters) at 4 consecutive d
                const float4 ev0 = *(const float4*)&es[(step * 4 + 0) * BK + tx * 4];
                const float4 ev1 = *(const float4*)&es[(step * 4 + 1) * BK + tx * 4];
                const float4 ev2 = *(const float4*)&es[(step * 4 + 2) * BK + tx * 4];
                const float4 ev3 = *(const float4*)&es[(step * 4 + 3) * BK + tx * 4];
                #pragma unroll
                for (int i = 0; i < TM; ++i) {
                    const float4 xv = *(const float4*)&xs[(ty * TM + i) * DC + step * 4];
                    acc[i][0] = fmaf(xv.x, ev0.x, acc[i][0]);
                    acc[i][0] = fmaf(xv.y, ev1.x, acc[i][0]);
                    acc[i][0] = fmaf(xv.z, ev2.x, acc[i][0]);
                    acc[i][0] = fmaf(xv.w, ev3.x, acc[i][0]);
                    acc[i][1] = fmaf(xv.x, ev0.y, acc[i][1]);
                    acc[i][1] = fmaf(xv.y, ev1.y, acc[i][1]);
                    acc[i][1] = fmaf(xv.z, ev2.y, acc[i][1]);
                    acc[i][1] = fmaf(xv.w, ev3.y, acc[i][1]);
                    acc[i][2] = fmaf(xv.x, ev0.z, acc[i][2]);
                    acc[i][2] = fmaf(xv.y, ev1.z, acc[i][2]);
                    acc[i][2] = fmaf(xv.z, ev2.z, acc[i][2]);
                    acc[i][2] = fmaf(xv.w, ev3.z, acc[i][2]);
                    acc[i][3] = fmaf(xv.x, ev0.w, acc[i][3]);
                    acc[i][3] = fmaf(xv.y, ev1.w, acc[i][3]);
                    acc[i][3] = fmaf(xv.z, ev2.w, acc[i][3]);
                    acc[i][3] = fmaf(xv.w, ev3.w, acc[i][3]);
                }
            }
        }

        // fold this K-tile into the running argmin
        #pragma unroll
        for (int j = 0; j < TK; ++j) {
            const int k = k0 + tx * TK + j;
            const float en = enorm2[k];
            #pragma unroll
            for (int i = 0; i < TM; ++i) {
                const float s = fmaf(-2.0f, acc[i][j], en);
                if (s < bestd[i]) { bestd[i] = s; bestk[i] = k; }
            }
        }
    }

    // reduce across the 32 lanes (tx) that share each row; ties -> smaller k
    #pragma unroll
    for (int i = 0; i < TM; ++i) {
        float bd = bestd[i];
        int   bk = bestk[i];
        #pragma unroll
        for (int off = 16; off > 0; off >>= 1) {
            const float od = __shfl_xor(bd, off, 64);
            const int   ok = __shfl_xor(bk, off, 64);
            if (od < bd || (od == bd && ok < bk)) { bd = od; bk = ok; }
        }
        if (tx == 0) {
            const int n = n0 + ty * TM + i;
            codes_i[n] = bk;
            codes_f[n] = (float)bk;
        }
    }
}

// ---------------- gather: quantized[n] = emb[code[n]] ----------------------
__global__ void gather_q(const float* __restrict__ emb,
                         const int* __restrict__ codes,
                         float* __restrict__ qout) {
    const int n = blockIdx.x * 4 + (threadIdx.x >> 6);
    const int c = threadIdx.x & 63;           // 64 lanes x float4 = 256 floats
    const int k = codes[n];
    *(float4*)&qout[(size_t)n * D + c * 4] =
        *(const float4*)&emb[(size_t)k * D + c * 4];
}

extern "C" void kernel_launch(void* const* d_in, const int* in_sizes, int n_in,
                              void* d_out, int out_size, void* d_ws, size_t ws_size,
                              hipStream_t stream) {
    const float* x     = (const float*)d_in[0];
    const float* esum  = (const float*)d_in[1];
    const float* usage = (const float*)d_in[2];
    const int K = in_sizes[2];                 // 2048
    const int N = in_sizes[0] / D;             // 32768

    float* ws      = (float*)d_ws;
    float* emb     = ws;                       // K*D
    float* emb_t   = ws + (size_t)K * D;       // K*D
    float* enorm2  = ws + (size_t)2 * K * D;   // K
    int*   codes_i = (int*)(ws + (size_t)2 * K * D + K);  // N

    float* qout    = (float*)d_out;            // N*D
    float* codes_f = qout + (size_t)N * D;     // N

    prep_emb<<<K, 256, 0, stream>>>(esum, usage, emb, emb_t, enorm2, K);
    vq_argmin<<<N / BN, 256, 0, stream>>>(x, emb_t, enorm2, codes_f, codes_i, K);
    gather_q<<<N / 4, 256, 0, stream>>>(emb, codes_i, qout);
}

// Round 2
// 388.872 us; speedup vs baseline: 1.1915x; 1.1915x over previous
//
#include <hip/hip_runtime.h>

// EuclideanCodebook via bf16x3-split MFMA distance + exact fp32 rescue.
// x: [N=32768][256] f32, embedding_sum: [K=2048][256] f32, usage: [K] f32
// out: quantized [N*256] f32, codes [N] f32

#define EPSV 1e-5f
#define DDIM 256
#define TAU  0.05f
#define BM   128     // rows per block
#define BCL  128     // clusters per tile
#define NCT  8       // cluster tiles per half (1024/128)
#define CHN  12      // inner chunks (768 = 12*64)

typedef __attribute__((ext_vector_type(8))) short bf16x8;
typedef __attribute__((ext_vector_type(4))) float f32x4;
typedef unsigned short u16;

__device__ __forceinline__ u16 f2bf(float f) {
    unsigned u = __builtin_bit_cast(unsigned, f);
    u = (u + 0x7fffu + ((u >> 16) & 1u)) >> 16;
    return (u16)u;
}
__device__ __forceinline__ float bf2f(u16 h) {
    unsigned u = ((unsigned)h) << 16;
    return __builtin_bit_cast(float, u);
}

// ---------------- prep_e: emb, e_hi, e_lo, ||e||^2 --------------------------
__global__ void prep_e(const float* __restrict__ esum,
                       const float* __restrict__ usage,
                       float* __restrict__ emb,     // [K][256] f32
                       u16* __restrict__ ehi,       // [K][256]
                       u16* __restrict__ elo,       // [K][256]
                       float* __restrict__ enorm2,  // [K]
                       int K) {
    const int k = blockIdx.x;
    const int d = threadIdx.x;                 // 256 threads
    const float u = fmaxf(usage[k], EPSV);
    const float e = esum[k * DDIM + d] / u;
    emb[k * DDIM + d] = e;
    const u16 h = f2bf(e);
    ehi[k * DDIM + d] = h;
    elo[k * DDIM + d] = f2bf(e - bf2f(h));

    float s = e * e;
    #pragma unroll
    for (int off = 32; off > 0; off >>= 1) s += __shfl_down(s, off, 64);
    __shared__ float ws[4];
    if ((threadIdx.x & 63) == 0) ws[threadIdx.x >> 6] = s;
    __syncthreads();
    if (threadIdx.x == 0) enorm2[k] = ws[0] + ws[1] + ws[2] + ws[3];
}

// ---------------- prep_x: x_hi, x_lo ----------------------------------------
__global__ void prep_x(const float* __restrict__ x,
                       u16* __restrict__ xhi, u16* __restrict__ xlo) {
    const int n = blockIdx.x * 4 + (threadIdx.x >> 6);
    const int l = threadIdx.x & 63;
    const float4 v = *(const float4*)&x[(size_t)n * DDIM + l * 4];
    ushort4 h, lo;
    h.x = f2bf(v.x); lo.x = f2bf(v.x - bf2f(h.x));
    h.y = f2bf(v.y); lo.y = f2bf(v.y - bf2f(h.y));
    h.z = f2bf(v.z); lo.z = f2bf(v.z - bf2f(h.z));
    h.w = f2bf(v.w); lo.w = f2bf(v.w - bf2f(h.w));
    *(ushort4*)&xhi[(size_t)n * DDIM + l * 4] = h;
    *(ushort4*)&xlo[(size_t)n * DDIM + l * 4] = lo;
}

// ---------------- main: MFMA distance + running (min1, idx, min2) ----------
__global__ __launch_bounds__(256, 2) void vq_mfma(
        const u16* __restrict__ xhi, const u16* __restrict__ xlo,
        const u16* __restrict__ ehi, const u16* __restrict__ elo,
        const float* __restrict__ enorm2,
        float* __restrict__ pm1, int* __restrict__ pi1,
        float* __restrict__ pm2, int N) {
    __shared__ u16 Als[BM * 64];    // 16 KB
    __shared__ u16 Bls[BCL * 64];   // 16 KB

    const int tid = threadIdx.x;
    const int l   = tid & 63;
    const int w   = tid >> 6;            // wave 0..3
    const int wr  = w >> 1, wc = w & 1;  // 2x2 wave grid (64x64 each)
    const int rowblk = blockIdx.x >> 1;
    const int half   = blockIdx.x & 1;
    const int n0     = rowblk * BM;
    const int cbase  = half * 1024;

    float m1[4][4], m2[4][4];
    int   i1[4][4];
    #pragma unroll
    for (int a = 0; a < 4; ++a)
        #pragma unroll
        for (int b = 0; b < 4; ++b) { m1[a][b] = 3.0e38f; m2[a][b] = 3.0e38f; i1[a][b] = 0; }

    for (int ct = 0; ct < NCT; ++ct) {
        const int c0 = cbase + ct * BCL;
        f32x4 acc[4][4];
        #pragma unroll
        for (int a = 0; a < 4; ++a)
            #pragma unroll
            for (int b = 0; b < 4; ++b) acc[a][b] = (f32x4){0.f, 0.f, 0.f, 0.f};

        for (int ch = 0; ch < CHN; ++ch) {
            // inner chunk ch of 768: A = [xhi | xhi | xlo], B = [ehi | elo | ehi]
            const u16* asrc = (ch < 8) ? xhi : xlo;
            const u16* bsrc = (ch < 4) ? ehi : ((ch < 8) ? elo : ehi);
            const int colof = (ch & 3) * 64;

            __syncthreads();
            #pragma unroll
            for (int j = 0; j < 4; ++j) {
                const int r = (w * 4 + j) * 8 + (l >> 3);
                const u16* ga = asrc + (size_t)(n0 + r) * DDIM + colof + (l & 7) * 8;
                __builtin_amdgcn_global_load_lds(
                    (const __attribute__((address_space(1))) void*)ga,
                    (__attribute__((address_space(3))) void*)((char*)Als + (w * 4 + j) * 1024),
                    16, 0, 0);
            }
            #pragma unroll
            for (int j = 0; j < 4; ++j) {
                const int r = (w * 4 + j) * 8 + (l >> 3);
                const u16* gb = bsrc + (size_t)(c0 + r) * DDIM + colof + (l & 7) * 8;
                __builtin_amdgcn_global_load_lds(
                    (const __attribute__((address_space(1))) void*)gb,
                    (__attribute__((address_space(3))) void*)((char*)Bls + (w * 4 + j) * 1024),
                    16, 0, 0);
            }
            __syncthreads();

            #pragma unroll
            for (int ks = 0; ks < 2; ++ks) {
                bf16x8 af[4], bfr[4];
                #pragma unroll
                for (int f = 0; f < 4; ++f) {
                    const int arow = wr * 64 + f * 16 + (l & 15);
                    af[f] = *(const bf16x8*)((const char*)Als + arow * 128 + ks * 64 + (l >> 4) * 16);
                    const int brow = wc * 64 + f * 16 + (l & 15);
                    bfr[f] = *(const bf16x8*)((const char*)Bls + brow * 128 + ks * 64 + (l >> 4) * 16);
                }
                #pragma unroll
                for (int fm = 0; fm < 4; ++fm)
                    #pragma unroll
                    for (int fn = 0; fn < 4; ++fn)
                        acc[fm][fn] = __builtin_amdgcn_mfma_f32_16x16x32_bf16(
                            af[fm], bfr[fn], acc[fm][fn], 0, 0, 0);
            }
        }

        // fold tile distances into running (min1, idx, min2); cols ascend in fn
        #pragma unroll
        for (int fn = 0; fn < 4; ++fn) {
            const int k = c0 + wc * 64 + fn * 16 + (l & 15);
            const float en = enorm2[k];
            #pragma unroll
            for (int fm = 0; fm < 4; ++fm)
                #pragma unroll
                for (int i = 0; i < 4; ++i) {
                    const float s = fmaf(-2.0f, acc[fm][fn][i], en);
                    const bool lt1 = s < m1[fm][i];
                    const bool lt2 = s < m2[fm][i];
                    m2[fm][i] = lt1 ? m1[fm][i] : (lt2 ? s : m2[fm][i]);
                    i1[fm][i] = lt1 ? k : i1[fm][i];
                    m1[fm][i] = lt1 ? s : m1[fm][i];
                }
        }
    }

    // reduce across the 16 lanes (l&15) that share rows
    #pragma unroll
    for (int fm = 0; fm < 4; ++fm)
        #pragma unroll
        for (int i = 0; i < 4; ++i) {
            float a1 = m1[fm][i], a2 = m2[fm][i];
            int ai = i1[fm][i];
            #pragma unroll
            for (int mask = 1; mask < 16; mask <<= 1) {
                const float b1 = __shfl_xor(a1, mask, 64);
                const int   bi = __shfl_xor(ai, mask, 64);
                const float b2 = __shfl_xor(a2, mask, 64);
                if (b1 < a1 || (b1 == a1 && bi < ai)) {
                    a2 = fminf(a1, fminf(a2, b2)); a1 = b1; ai = bi;
                } else {
                    a2 = fminf(b1, fminf(a2, b2));
                }
            }
            m1[fm][i] = a1; i1[fm][i] = ai; m2[fm][i] = a2;
        }

    // merge the two wave-columns via LDS, write per-(half,row) partials
    __syncthreads();
    float* Sm1 = (float*)Als;
    int*   Si1 = (int*)((char*)Als + 512);
    float* Sm2 = (float*)((char*)Als + 1024);
    if (wc == 0 && (l & 15) == 0) {
        #pragma unroll
        for (int fm = 0; fm < 4; ++fm)
            #pragma unroll
            for (int i = 0; i < 4; ++i) {
                const int r = wr * 64 + fm * 16 + (l >> 4) * 4 + i;
                Sm1[r] = m1[fm][i]; Si1[r] = i1[fm][i]; Sm2[r] = m2[fm][i];
            }
    }
    __syncthreads();
    if (wc == 1 && (l & 15) == 0) {
        #pragma unroll
        for (int fm = 0; fm < 4; ++fm)
            #pragma unroll
            for (int i = 0; i < 4; ++i) {
                const int r = wr * 64 + fm * 16 + (l >> 4) * 4 + i;
                const float b1 = Sm1[r], b2 = Sm2[r];
                const int   bi = Si1[r];
                float a1 = m1[fm][i], a2 = m2[fm][i];
                int   ai = i1[fm][i];
                float M1, M2; int MI;
                if (b1 < a1 || (b1 == a1 && bi < ai)) {
                    M1 = b1; MI = bi; M2 = fminf(a1, fminf(a2, b2));
                } else {
                    M1 = a1; MI = ai; M2 = fminf(b1, fminf(a2, b2));
                }
                const int n = n0 + r;
                pm1[(size_t)half * N + n] = M1;
                pi1[(size_t)half * N + n] = MI;
                pm2[(size_t)half * N + n] = M2;
            }
    }
}

// ---------------- combine halves -> codes + flags ---------------------------
__global__ void combine(const float* __restrict__ pm1, const int* __restrict__ pi1,
                        const float* __restrict__ pm2,
                        float* __restrict__ codes_f, int* __restrict__ codes_i,
                        int* __restrict__ flags, int N) {
    const int n = blockIdx.x * 256 + threadIdx.x;
    const float a1 = pm1[n], a2 = pm2[n];
    const int   ai = pi1[n];
    const float b1 = pm1[(size_t)N + n], b2 = pm2[(size_t)N + n];
    const int   bi = pi1[(size_t)N + n];
    float M1, M2; int MI;
    if (b1 < a1 || (b1 == a1 && bi < ai)) {
        M1 = b1; MI = bi; M2 = fminf(a1, fminf(a2, b2));
    } else {
        M1 = a1; MI = ai; M2 = fminf(b1, fminf(a2, b2));
    }
    codes_i[n] = MI;
    codes_f[n] = (float)MI;
    flags[n] = (M2 - M1 < TAU) ? 1 : 0;
}

// ---------------- rescue: exact fp32 re-score for flagged rows --------------
__global__ __launch_bounds__(256) void rescue(
        const float* __restrict__ x, const float* __restrict__ emb,
        const float* __restrict__ enorm2, const int* __restrict__ flags,
        float* __restrict__ codes_f, int* __restrict__ codes_i, int K) {
    __shared__ float xs[4][DDIM];
    const int wv = threadIdx.x >> 6;
    const int l  = threadIdx.x & 63;
    const int n  = blockIdx.x * 4 + wv;
    if (!flags[n]) return;                      // wave-uniform exit

    *(float4*)&xs[wv][l * 4] = *(const float4*)&x[(size_t)n * DDIM + l * 4];

    float best = 3.0e38f;
    int   bk = 0;
    for (int c = 0; c < K / 64; ++c) {
        const int k = c * 64 + l;               // ascending k per lane
        float dot = 0.f;
        #pragma unroll 16
        for (int d = 0; d < DDIM; d += 4) {
            const float4 e = *(const float4*)&emb[(size_t)k * DDIM + d];
            dot = fmaf(xs[wv][d + 0], e.x, dot);
            dot = fmaf(xs[wv][d + 1], e.y, dot);
            dot = fmaf(xs[wv][d + 2], e.z, dot);
            dot = fmaf(xs[wv][d + 3], e.w, dot);
        }
        const float s = fmaf(-2.0f, dot, enorm2[k]);
        if (s < best) { best = s; bk = k; }
    }
    #pragma unroll
    for (int mask = 1; mask < 64; mask <<= 1) {
        const float ob = __shfl_xor(best, mask, 64);
        const int   ok = __shfl_xor(bk, mask, 64);
        if (ob < best || (ob == best && ok < bk)) { best = ob; bk = ok; }
    }
    if (l == 0) { codes_i[n] = bk; codes_f[n] = (float)bk; }
}

// ---------------- gather: quantized[n] = emb[code[n]] -----------------------
__global__ void gather_q(const float* __restrict__ emb,
                         const int* __restrict__ codes,
                         float* __restrict__ qout) {
    const int n = blockIdx.x * 4 + (threadIdx.x >> 6);
    const int c = threadIdx.x & 63;
    const int k = codes[n];
    *(float4*)&qout[(size_t)n * DDIM + c * 4] =
        *(const float4*)&emb[(size_t)k * DDIM + c * 4];
}

extern "C" void kernel_launch(void* const* d_in, const int* in_sizes, int n_in,
                              void* d_out, int out_size, void* d_ws, size_t ws_size,
                              hipStream_t stream) {
    const float* x     = (const float*)d_in[0];
    const float* esum  = (const float*)d_in[1];
    const float* usage = (const float*)d_in[2];
    const int K = in_sizes[2];                 // 2048
    const int N = in_sizes[0] / DDIM;          // 32768

    // workspace layout
    char* p = (char*)d_ws;
    float* emb     = (float*)p;                p += (size_t)K * DDIM * 4;   // 2 MB
    float* enorm2  = (float*)p;                p += (size_t)K * 4;
    float* pm1     = (float*)p;                p += (size_t)2 * N * 4;
    float* pm2     = (float*)p;                p += (size_t)2 * N * 4;
    int*   pi1     = (int*)p;                  p += (size_t)2 * N * 4;
    int*   codes_i = (int*)p;                  p += (size_t)N * 4;
    int*   flags   = (int*)p;                  p += (size_t)N * 4;
    u16*   xhi     = (u16*)p;                  p += (size_t)N * DDIM * 2;   // 16 MB
    u16*   xlo     = (u16*)p;                  p += (size_t)N * DDIM * 2;   // 16 MB
    u16*   ehi     = (u16*)p;                  p += (size_t)K * DDIM * 2;   // 1 MB
    u16*   elo     = (u16*)p;                  p += (size_t)K * DDIM * 2;   // 1 MB

    float* qout    = (float*)d_out;            // N*256
    float* codes_f = qout + (size_t)N * DDIM;  // N

    prep_e<<<K, 256, 0, stream>>>(esum, usage, emb, ehi, elo, enorm2, K);
    prep_x<<<N / 4, 256, 0, stream>>>(x, xhi, xlo);
    vq_mfma<<<(N / BM) * 2, 256, 0, stream>>>(xhi, xlo, ehi, elo, enorm2,
                                              pm1, pi1, pm2, N);
    combine<<<N / 256, 256, 0, stream>>>(pm1, pi1, pm2, codes_f, codes_i, flags, N);
    rescue<<<N / 4, 256, 0, stream>>>(x, emb, enorm2, flags, codes_f, codes_i, K);
    gather_q<<<N / 4, 256, 0, stream>>>(emb, codes_i, qout);
}